// Round 1
// baseline (310.970 us; speedup 1.0000x reference)
//
#include <hip/hip_runtime.h>

#define BLK 256
#define DD  48
#define PAD 49                       // LDS row stride in floats; bank stride = 49 mod 32 = 17 (odd)
                                     // -> lane->bank map bijective mod 32 -> <=2-way conflicts (free)
#define INV2PI 0.15915494309189535f  // v_sin/v_cos take revolutions

// rho = a0*I + v.sigma (a0, v complex). Conjugation by U_k = Rz(-p1k)Ry(p0k)Rz(-p2k)
// leaves a0 invariant and rotates v. Adjacent Rz's across blocks merge:
//   Z(-p2_0), then for k=0..14: Y(p0_k), Z(-(p1_k + p2_{k+1})), then Y(p0_15), Z(-p1_15)
// => 33 rotations / 33 native sincos instead of 48.
//
// R6 change vs R5: x-row access. Old: each lane read its own 192B row via 12
// float4 loads at 192B inter-lane stride -> ~64 cache lines per VMEM instr
// (4x transactions) + L1 thrash across waves. New: cooperative LDS staging —
// each block stages its contiguous 48 KiB x-tile with perfectly coalesced
// float4 loads, then reads rows from padded LDS.
__global__ __launch_bounds__(BLK) void qlayer_kernel(
    const float* __restrict__ rho_real,
    const float* __restrict__ rho_imag,
    const float* __restrict__ x,
    const float* __restrict__ w,
    const float* __restrict__ theta,
    float* __restrict__ out,
    long long n,            // number of elements B
    long long out_floats)   // d_out capacity in floats (4*n: REAL part only)
{
    __shared__ float xls[BLK * PAD];   // 50176 B -> 3 blocks/CU (12 waves/CU)

    const long long blockBase = (long long)blockIdx.x * BLK;
    const int tid = threadIdx.x;
    const long long b = blockBase + tid;

    // ---- Stage x tile (BLK rows x 48 f32 = 48 KiB), fully coalesced ----
    // lane g loads float4 #g of the contiguous tile: 16B/lane, unit stride.
    const float4* __restrict__ xg = reinterpret_cast<const float4*>(x + blockBase * DD);
    long long rem = n - blockBase;
    const int nrows = (int)(rem < (long long)BLK ? rem : (long long)BLK);
    #pragma unroll
    for (int i = 0; i < 12; ++i) {
        const int g   = i * BLK + tid;       // float4 index within tile [0, 3072)
        const int row = g / 12;              // 12 float4 per row
        const int c   = (g - row * 12) * 4;  // float column
        if (row < nrows) {
            const float4 v = xg[g];
            float* dst = &xls[row * PAD + c];
            dst[0] = v.x; dst[1] = v.y; dst[2] = v.z; dst[3] = v.w;
        }
    }

    // rho loads are independent of LDS -> issue before the barrier so their
    // latency overlaps the staging.
    float4 rr = make_float4(0.f, 0.f, 0.f, 0.f);
    float4 ri = make_float4(0.f, 0.f, 0.f, 0.f);
    if (b < n) {
        rr = reinterpret_cast<const float4*>(rho_real)[b];
        ri = reinterpret_cast<const float4*>(rho_imag)[b];
    }

    __syncthreads();
    if (b >= n) return;

    // --- Bloch decomposition ---
    float a0r = 0.5f * (rr.x + rr.w);
    float v1r = 0.5f * (rr.y + rr.z), v1i = 0.5f * (ri.y + ri.z);
    float v2r = 0.5f * (ri.z - ri.y), v2i = 0.5f * (rr.y - rr.z);
    float v3r = 0.5f * (rr.x - rr.w), v3i = 0.5f * (ri.x - ri.w);

    // This thread's x row in LDS. Bank(addr) = (17*tid + col) mod 32 -> all
    // 32 banks covered across a wave, 2 lanes/bank worst case (free).
    const float* __restrict__ xr = &xls[tid * PAD];

    // Plane-rotation helpers (native HW trig). Angle semantics match the
    // verified R5 kernel: rotZ(a) == Rz(-a) on (v1,v2); rotY(a) == Ry(a) on (v1,v3).
    auto rotZ = [&](float ang) {
        float s = __builtin_amdgcn_sinf(ang * INV2PI);
        float c = __builtin_amdgcn_cosf(ang * INV2PI);
        float t1r = fmaf(c, v1r,  s * v2r);
        float t1i = fmaf(c, v1i,  s * v2i);
        v2r = fmaf(c, v2r, -s * v1r);
        v2i = fmaf(c, v2i, -s * v1i);
        v1r = t1r; v1i = t1i;
    };
    auto rotY = [&](float ang) {
        float s = __builtin_amdgcn_sinf(ang * INV2PI);
        float c = __builtin_amdgcn_cosf(ang * INV2PI);
        float t1r = fmaf(c, v1r,  s * v3r);
        float t1i = fmaf(c, v1i,  s * v3i);
        v3r = fmaf(c, v3r, -s * v1r);
        v3i = fmaf(c, v3i, -s * v1i);
        v1r = t1r; v1i = t1i;
    };

    // --- Merged rotation chain ---
    rotZ(fmaf(xr[2], w[2], theta[2]));                       // Z(-p2_0)
    #pragma unroll
    for (int k = 0; k < 15; ++k) {
        const int j = 3 * k;
        rotY(fmaf(xr[j], w[j], theta[j]));                   // Y(p0_k)
        // Z(-(p1_k + p2_{k+1})): theta-sum is scalar math (compile-time idx)
        float ts = theta[j + 1] + theta[j + 5];
        rotZ(fmaf(xr[j + 1], w[j + 1], fmaf(xr[j + 5], w[j + 5], ts)));
    }
    rotY(fmaf(xr[45], w[45], theta[45]));                    // Y(p0_15)
    rotZ(fmaf(xr[46], w[46], theta[46]));                    // Z(-p1_15)

    // --- Reassemble REAL parts only ---
    if (4 * b + 4 <= out_floats) {
        reinterpret_cast<float4*>(out)[b] =
            make_float4(a0r + v3r, v1r + v2i, v1r - v2i, a0r - v3r);
    } else {
        float vals[4] = {a0r + v3r, v1r + v2i, v1r - v2i, a0r - v3r};
        for (int j = 0; j < 4; ++j) {
            long long o = 4 * b + j;
            if (o < out_floats) out[o] = vals[j];
        }
    }
}

extern "C" void kernel_launch(void* const* d_in, const int* in_sizes, int n_in,
                              void* d_out, int out_size, void* d_ws, size_t ws_size,
                              hipStream_t stream) {
    const float* rho_real = (const float*)d_in[0];
    const float* rho_imag = (const float*)d_in[1];
    const float* x        = (const float*)d_in[2];
    const float* w        = (const float*)d_in[3];
    const float* theta    = (const float*)d_in[4];
    float* out = (float*)d_out;

    long long nB = (long long)in_sizes[0] / 4;
    long long nX = (long long)in_sizes[2] / DD;
    long long n  = nB < nX ? nB : nX;
    if (n <= 0) return;

    int grid = (int)((n + BLK - 1) / BLK);
    qlayer_kernel<<<dim3(grid), dim3(BLK), 0, stream>>>(
        rho_real, rho_imag, x, w, theta, out, n, (long long)out_size);
}